// Round 4
// baseline (95.052 us; speedup 1.0000x reference)
//
#include <hip/hip_runtime.h>

namespace {

constexpr int kBevH = 188, kBevW = 126, kP = kBevH * kBevW;   // 23688
constexpr int kB = 2, kN = 6, kC = 256, kHf = 48, kWf = 96;
constexpr int kHW = kHf * kWf;                                // 4608
constexpr int kPTile = 32;
constexpr int kNTiles = (kP + kPTile - 1) / kPTile;           // 741
constexpr size_t kImgBytes  = (size_t)kB * kN * kHW * kC * 2; // 28.3 MB bf16
constexpr size_t kRecCount  = (size_t)kB * kP * (size_t)kN;   // 284256
constexpr size_t kOffsBytes = kRecCount * 16;
constexpr size_t kWtsBytes  = kRecCount * 16;
constexpr size_t kMaskBytes = (size_t)kB * kP * 4;
constexpr size_t kWsNeeded  = kImgBytes + kOffsBytes + kWtsBytes + kMaskBytes;

__device__ __forceinline__ unsigned short f2bf(float f) {     // RNE, finite inputs
  union { float f; unsigned u; } a; a.f = f;
  unsigned r = a.u + 0x7fffu + ((a.u >> 16) & 1u);
  return (unsigned short)(r >> 16);
}
__device__ __forceinline__ float bfl(unsigned u) {
  union { unsigned u; float f; } a; a.u = u << 16; return a.f;
}
__device__ __forceinline__ float bfh(unsigned u) {
  union { unsigned u; float f; } a; a.u = u & 0xffff0000u; return a.f;
}

// ---------------- K0: per-(b,p) projection -> tap records ----------------
__global__ __launch_bounds__(256) void taps_kernel(
    const float* __restrict__ intr, const float* __restrict__ c2c,
    int4* __restrict__ offs, float4* __restrict__ wts, int* __restrict__ vm) {
  const int gid = blockIdx.x * 256 + threadIdx.x;
  if (gid >= kB * kP) return;
  const int b = gid / kP, p = gid - b * kP;
  const int pi = p / kBevW, pj = p - pi * kBevW;
  const float dx = 75.2f / 188.0f, dy = 50.4f / 126.0f;
  const float xcar = 0.5f * dx + (float)pi * dx;
  const float ycar = -25.2f + 0.5f * dy + (float)pj * dy;
  const float* Kb = intr + (size_t)b * kN * 9;
  const float* Mb = c2c + (size_t)b * kN * 16;
  int vmask = 0;
#pragma unroll
  for (int n = 0; n < kN; ++n) {
    const float* M = Mb + n * 16;
    const float* K = Kb + n * 9;
    float Xc = M[0] * xcar + M[1] * ycar + M[3];
    float Yc = M[4] * xcar + M[5] * ycar + M[7];
    float Zc = M[8] * xcar + M[9] * ycar + M[11];
    float u = K[0] * Xc + K[1] * Yc + K[2] * Zc;
    float v = K[3] * Xc + K[4] * Yc + K[5] * Zc;
    float w = K[6] * Xc + K[7] * Yc + K[8] * Zc;
    float z = fmaxf(w, 1e-4f);
    float uf = (u / z) * 0.125f;
    float vf = (v / z) * 0.125f;
    bool valid = (Zc > 0.1f) && (uf >= 0.0f) && (uf <= 95.0f) &&
                 (vf >= 0.0f) && (vf <= 47.0f);
    if (valid) {
      // reproduce reference op order (norm round-trip)
      float un = (uf / 95.0f) * 2.0f - 1.0f;
      float vn = (vf / 47.0f) * 2.0f - 1.0f;
      float ix = (un + 1.0f) * 0.5f * 95.0f;
      float iy = (vn + 1.0f) * 0.5f * 47.0f;
      float x0f = floorf(ix), y0f = floorf(iy);
      float wx1 = ix - x0f, wx0 = 1.0f - wx1;
      float wy1 = iy - y0f, wy0 = 1.0f - wy1;
      int o[4]; float wt[4];
#pragma unroll
      for (int t = 0; t < 4; ++t) {
        float xf = x0f + (float)(t & 1);
        float yf = y0f + (float)(t >> 1);
        bool inb = (xf >= 0.0f) && (xf <= 95.0f) && (yf >= 0.0f) &&
                   (yf <= 47.0f);
        int xi = (int)fminf(fmaxf(xf, 0.0f), 95.0f);
        int yi = (int)fminf(fmaxf(yf, 0.0f), 47.0f);
        float wgt = ((t & 1) ? wx1 : wx0) * ((t >> 1) ? wy1 : wy0);
        o[t] = (((b * kN + n) * kHW) + yi * kWf + xi) * (kC * 2);  // byte off
        wt[t] = inb ? wgt : 0.0f;
      }
      offs[(size_t)gid * kN + n] = make_int4(o[0], o[1], o[2], o[3]);
      wts[(size_t)gid * kN + n] = make_float4(wt[0], wt[1], wt[2], wt[3]);
      vmask |= (1 << n);
    }
  }
  vm[gid] = vmask;
}

// ------------- K1: feats f32 [B,N,C,H,W] -> bf16 [B,N,HW,C] --------------
__global__ __launch_bounds__(256) void transpose_cvt_kernel(
    const float* __restrict__ src, unsigned short* __restrict__ dst) {
  __shared__ float tile[64][33];
  const int m = blockIdx.z;
  const int hw0 = blockIdx.x * 32;
  const int c0 = blockIdx.y * 64;
  const float* s = src + (size_t)m * kC * kHW;
  unsigned short* d = dst + (size_t)m * kHW * kC;
  const int hw = threadIdx.x & 31, cl = threadIdx.x >> 5;
#pragma unroll
  for (int k = 0; k < 8; ++k)
    tile[cl + 8 * k][hw] = s[(size_t)(c0 + cl + 8 * k) * kHW + hw0 + hw];
  __syncthreads();
  const int cp = threadIdx.x & 31, hwl = threadIdx.x >> 5;
#pragma unroll
  for (int k = 0; k < 4; ++k) {
    const int h = hwl + 8 * k;
    ushort2 uv;
    uv.x = f2bf(tile[2 * cp][h]);
    uv.y = f2bf(tile[2 * cp + 1][h]);
    *(ushort2*)(d + (size_t)(hw0 + h) * kC + c0 + 2 * cp) = uv;
  }
}

// ------------- K2: gather, full-wave-per-pixel, LDS out transpose --------
__global__ __launch_bounds__(256) void gather_kernel(
    const unsigned char* __restrict__ tf, const int4* __restrict__ offs,
    const float4* __restrict__ wts, const int* __restrict__ vm,
    float* __restrict__ out) {
  __shared__ float sm[kPTile][260];
  const int b = blockIdx.y;
  // bijective XCD swizzle (m204): adjacent p-tiles -> same XCD's L2
  const int orig = blockIdx.x;
  constexpr int q = kNTiles / 8, r = kNTiles % 8;  // 92, 5
  const int xcd = orig & 7, idx = orig >> 3;
  const int tile = (xcd < r ? xcd * (q + 1) : r * (q + 1) + (xcd - r) * q) + idx;
  const int p0 = tile * kPTile;
  const int tid = threadIdx.x;
  const int w = tid >> 6, l = tid & 63;
  const float inv_n = 1.0f / 6.0f;

#pragma unroll 2
  for (int j = 0; j < 8; ++j) {
    const int pl = w * 8 + j;
    const int p = p0 + pl;
    if (p < kP) {
      const int vmask = vm[b * kP + p];
      const size_t rec = ((size_t)(b * kP + p)) * kN;
      float ax = 0.f, ay = 0.f, az = 0.f, aw = 0.f;
#pragma unroll
      for (int n = 0; n < kN; ++n) {
        if (vmask & (1 << n)) {
          const int4 o = offs[rec + n];
          const float4 wt = wts[rec + n];
          // lane l covers channels 4l..4l+3 (8B of the 512B pixel vector)
          const uint2 d0 = *(const uint2*)(tf + o.x + (l << 3));
          const uint2 d1 = *(const uint2*)(tf + o.y + (l << 3));
          const uint2 d2 = *(const uint2*)(tf + o.z + (l << 3));
          const uint2 d3 = *(const uint2*)(tf + o.w + (l << 3));
          ax += wt.x * bfl(d0.x); ay += wt.x * bfh(d0.x);
          az += wt.x * bfl(d0.y); aw += wt.x * bfh(d0.y);
          ax += wt.y * bfl(d1.x); ay += wt.y * bfh(d1.x);
          az += wt.y * bfl(d1.y); aw += wt.y * bfh(d1.y);
          ax += wt.z * bfl(d2.x); ay += wt.z * bfh(d2.x);
          az += wt.z * bfl(d2.y); aw += wt.z * bfh(d2.y);
          ax += wt.w * bfl(d3.x); ay += wt.w * bfh(d3.x);
          az += wt.w * bfl(d3.y); aw += wt.w * bfh(d3.y);
        }
      }
      float4 res = make_float4(ax * inv_n, ay * inv_n, az * inv_n, aw * inv_n);
      *(float4*)&sm[pl][l << 2] = res;
    }
  }
  __syncthreads();
  // write: 8 rounds; instr = 8 c-rows x 32 consecutive p (coalesced)
#pragma unroll
  for (int rd = 0; rd < 8; ++rd) {
    const int cr = rd * 32 + (tid >> 3);
    const int p4 = (tid & 7) * 4;
    const int pg = p0 + p4;
    if (pg < kP) {  // kP%4==0 -> whole float4 chunk valid
      float4 v = make_float4(sm[p4][cr], sm[p4 + 1][cr], sm[p4 + 2][cr],
                             sm[p4 + 3][cr]);
      *(float4*)(out + ((size_t)(b * kC + cr)) * kP + pg) = v;
    }
  }
}

// ---------------- Fallback (R0 kernel) if ws too small -------------------
constexpr int kCChunk = 32;
__global__ __launch_bounds__(256) void ipm_project_kernel(
    const float* __restrict__ feats, const float* __restrict__ intr,
    const float* __restrict__ c2c, float* __restrict__ out) {
  const int p = blockIdx.x * 256 + threadIdx.x;
  const int b = blockIdx.y;
  const int c0 = blockIdx.z * kCChunk;
  const bool inrange = p < kP;
  const int pi = p / kBevW;
  const int pj = p - pi * kBevW;
  const float dx = 75.2f / 188.0f;
  const float dy = 50.4f / 126.0f;
  const float xcar = 0.5f * dx + (float)pi * dx;
  const float ycar = -25.2f + 0.5f * dy + (float)pj * dy;
  int tap[kN][4];
  float tw[kN][4];
  int vmask = 0;
  const float* Kb = intr + (size_t)b * kN * 9;
  const float* Mb = c2c + (size_t)b * kN * 16;
#pragma unroll
  for (int n = 0; n < kN; ++n) {
    const float* M = Mb + n * 16;
    const float* K = Kb + n * 9;
    float Xc = M[0] * xcar + M[1] * ycar + M[3];
    float Yc = M[4] * xcar + M[5] * ycar + M[7];
    float Zc = M[8] * xcar + M[9] * ycar + M[11];
    float u = K[0] * Xc + K[1] * Yc + K[2] * Zc;
    float v = K[3] * Xc + K[4] * Yc + K[5] * Zc;
    float w = K[6] * Xc + K[7] * Yc + K[8] * Zc;
    float z = fmaxf(w, 1e-4f);
    float uf = (u / z) * 0.125f;
    float vf = (v / z) * 0.125f;
    bool valid = inrange && (Zc > 0.1f) && (uf >= 0.0f) && (uf <= 95.0f) &&
                 (vf >= 0.0f) && (vf <= 47.0f);
    if (valid) {
      float un = (uf / 95.0f) * 2.0f - 1.0f;
      float vn = (vf / 47.0f) * 2.0f - 1.0f;
      float ix = (un + 1.0f) * 0.5f * 95.0f;
      float iy = (vn + 1.0f) * 0.5f * 47.0f;
      float x0f = floorf(ix), y0f = floorf(iy);
      float wx1 = ix - x0f, wx0 = 1.0f - wx1;
      float wy1 = iy - y0f, wy0 = 1.0f - wy1;
#pragma unroll
      for (int t = 0; t < 4; ++t) {
        float xf = x0f + (float)(t & 1);
        float yf = y0f + (float)(t >> 1);
        bool inb =
            (xf >= 0.0f) && (xf <= 95.0f) && (yf >= 0.0f) && (yf <= 47.0f);
        int xi = (int)fminf(fmaxf(xf, 0.0f), 95.0f);
        int yi = (int)fminf(fmaxf(yf, 0.0f), 47.0f);
        float wgt = ((t & 1) ? wx1 : wx0) * ((t >> 1) ? wy1 : wy0);
        tap[n][t] = yi * kWf + xi;
        tw[n][t] = inb ? wgt : 0.0f;
      }
      vmask |= (1 << n);
    }
  }
  const float inv_n = 1.0f / 6.0f;
#pragma unroll 4
  for (int k = 0; k < kCChunk; ++k) {
    const int c = c0 + k;
    float acc = 0.0f;
#pragma unroll
    for (int n = 0; n < kN; ++n) {
      if (vmask & (1 << n)) {
        const float* f = feats + ((size_t)(b * kN + n) * kC + c) * kHW;
        acc += f[tap[n][0]] * tw[n][0] + f[tap[n][1]] * tw[n][1] +
               f[tap[n][2]] * tw[n][2] + f[tap[n][3]] * tw[n][3];
      }
    }
    if (inrange) out[((size_t)b * kC + c) * kP + p] = acc * inv_n;
  }
}

}  // namespace

extern "C" void kernel_launch(void* const* d_in, const int* in_sizes, int n_in,
                              void* d_out, int out_size, void* d_ws,
                              size_t ws_size, hipStream_t stream) {
  const float* feats = (const float*)d_in[0];
  const float* intr = (const float*)d_in[1];
  const float* c2c = (const float*)d_in[2];
  float* out = (float*)d_out;

  if (ws_size >= kWsNeeded && d_ws != nullptr) {
    unsigned char* wsb = (unsigned char*)d_ws;
    unsigned short* tf = (unsigned short*)wsb;
    int4* offs = (int4*)(wsb + kImgBytes);
    float4* wtsp = (float4*)(wsb + kImgBytes + kOffsBytes);
    int* vm = (int*)(wsb + kImgBytes + kOffsBytes + kWtsBytes);

    taps_kernel<<<(kB * kP + 255) / 256, 256, 0, stream>>>(intr, c2c, offs,
                                                           wtsp, vm);
    transpose_cvt_kernel<<<dim3(kHW / 32, kC / 64, kB * kN), 256, 0, stream>>>(
        feats, tf);
    gather_kernel<<<dim3(kNTiles, kB), 256, 0, stream>>>(
        (const unsigned char*)tf, offs, wtsp, vm, out);
  } else {
    dim3 grid((kP + 255) / 256, kB, kC / kCChunk);
    ipm_project_kernel<<<grid, dim3(256), 0, stream>>>(feats, intr, c2c, out);
  }
}

// Round 5
// 65.705 us; speedup vs baseline: 1.4467x; 1.4467x over previous
//
#include <hip/hip_runtime.h>

namespace {

constexpr int kBevH = 188, kBevW = 126, kP = kBevH * kBevW;   // 23688
constexpr int kB = 2, kN = 6, kC = 256, kHf = 48, kWf = 96;
constexpr int kHW = kHf * kWf;                                // 4608
constexpr int kPTile = 32;
constexpr int kNTiles = (kP + kPTile - 1) / kPTile;           // 741
constexpr size_t kImgBytes  = (size_t)kB * kN * kHW * kC * 2; // 28.3 MB bf16
constexpr size_t kRecCount  = (size_t)kB * kP * (size_t)kN;   // 284256
constexpr size_t kOffsBytes = kRecCount * 16;
constexpr size_t kWtsBytes  = kRecCount * 16;
constexpr size_t kWsNeeded  = kImgBytes + kOffsBytes + kWtsBytes;

__device__ __forceinline__ unsigned short f2bf(float f) {     // RNE, finite
  union { float f; unsigned u; } a; a.f = f;
  unsigned r = a.u + 0x7fffu + ((a.u >> 16) & 1u);
  return (unsigned short)(r >> 16);
}
__device__ __forceinline__ float bfl(unsigned u) {
  union { unsigned u; float f; } a; a.u = u << 16; return a.f;
}
__device__ __forceinline__ float bfh(unsigned u) {
  union { unsigned u; float f; } a; a.u = u & 0xffff0000u; return a.f;
}

// ---------------- K0: per-(b,p) projection -> tap records ----------------
// ALWAYS writes all 6 records (zero weight/offset for invalid cams) so the
// gather can be branchless.
__global__ __launch_bounds__(256) void taps_kernel(
    const float* __restrict__ intr, const float* __restrict__ c2c,
    int4* __restrict__ offs, float4* __restrict__ wts) {
  const int gid = blockIdx.x * 256 + threadIdx.x;
  if (gid >= kB * kP) return;
  const int b = gid / kP, p = gid - b * kP;
  const int pi = p / kBevW, pj = p - pi * kBevW;
  const float dx = 75.2f / 188.0f, dy = 50.4f / 126.0f;
  const float xcar = 0.5f * dx + (float)pi * dx;
  const float ycar = -25.2f + 0.5f * dy + (float)pj * dy;
  const float* Kb = intr + (size_t)b * kN * 9;
  const float* Mb = c2c + (size_t)b * kN * 16;
#pragma unroll
  for (int n = 0; n < kN; ++n) {
    const float* M = Mb + n * 16;
    const float* K = Kb + n * 9;
    float Xc = M[0] * xcar + M[1] * ycar + M[3];
    float Yc = M[4] * xcar + M[5] * ycar + M[7];
    float Zc = M[8] * xcar + M[9] * ycar + M[11];
    float u = K[0] * Xc + K[1] * Yc + K[2] * Zc;
    float v = K[3] * Xc + K[4] * Yc + K[5] * Zc;
    float w = K[6] * Xc + K[7] * Yc + K[8] * Zc;
    float z = fmaxf(w, 1e-4f);
    float uf = (u / z) * 0.125f;
    float vf = (v / z) * 0.125f;
    bool valid = (Zc > 0.1f) && (uf >= 0.0f) && (uf <= 95.0f) &&
                 (vf >= 0.0f) && (vf <= 47.0f);
    int4 ov = make_int4(0, 0, 0, 0);
    float4 wv = make_float4(0.f, 0.f, 0.f, 0.f);
    if (valid) {
      // reproduce reference op order (norm round-trip)
      float un = (uf / 95.0f) * 2.0f - 1.0f;
      float vn = (vf / 47.0f) * 2.0f - 1.0f;
      float ix = (un + 1.0f) * 0.5f * 95.0f;
      float iy = (vn + 1.0f) * 0.5f * 47.0f;
      float x0f = floorf(ix), y0f = floorf(iy);
      float wx1 = ix - x0f, wx0 = 1.0f - wx1;
      float wy1 = iy - y0f, wy0 = 1.0f - wy1;
      int o[4]; float wt[4];
#pragma unroll
      for (int t = 0; t < 4; ++t) {
        float xf = x0f + (float)(t & 1);
        float yf = y0f + (float)(t >> 1);
        bool inb = (xf >= 0.0f) && (xf <= 95.0f) && (yf >= 0.0f) &&
                   (yf <= 47.0f);
        int xi = (int)fminf(fmaxf(xf, 0.0f), 95.0f);
        int yi = (int)fminf(fmaxf(yf, 0.0f), 47.0f);
        float wgt = ((t & 1) ? wx1 : wx0) * ((t >> 1) ? wy1 : wy0);
        o[t] = (((b * kN + n) * kHW) + yi * kWf + xi) * (kC * 2);  // byte off
        wt[t] = inb ? wgt : 0.0f;
      }
      ov = make_int4(o[0], o[1], o[2], o[3]);
      wv = make_float4(wt[0], wt[1], wt[2], wt[3]);
    }
    offs[(size_t)gid * kN + n] = ov;
    wts[(size_t)gid * kN + n] = wv;
  }
}

// ------------- K1: feats f32 [B,N,C,H,W] -> bf16 [B,N,HW,C] --------------
__global__ __launch_bounds__(256) void transpose_cvt_kernel(
    const float* __restrict__ src, unsigned short* __restrict__ dst) {
  __shared__ float tile[64][33];
  const int m = blockIdx.z;
  const int hw0 = blockIdx.x * 32;
  const int c0 = blockIdx.y * 64;
  const float* s = src + (size_t)m * kC * kHW;
  unsigned short* d = dst + (size_t)m * kHW * kC;
  const int hw = threadIdx.x & 31, cl = threadIdx.x >> 5;
#pragma unroll
  for (int k = 0; k < 8; ++k)
    tile[cl + 8 * k][hw] = s[(size_t)(c0 + cl + 8 * k) * kHW + hw0 + hw];
  __syncthreads();
  const int cp = threadIdx.x & 31, hwl = threadIdx.x >> 5;
#pragma unroll
  for (int k = 0; k < 4; ++k) {
    const int h = hwl + 8 * k;
    ushort2 uv;
    uv.x = f2bf(tile[2 * cp][h]);
    uv.y = f2bf(tile[2 * cp + 1][h]);
    *(ushort2*)(d + (size_t)(hw0 + h) * kC + c0 + 2 * cp) = uv;
  }
}

// ------------- K2: branchless batched gather ------------------------------
// Block = 4 waves, 32 p, all 256 c. Wave w owns p = p0+8w..p0+8w+7.
// Per p: 24 INDEPENDENT uint2 loads issued back-to-back (deep MLP), then
// consumed. Records are wave-uniform -> readfirstlane -> s_load path.
__global__ __launch_bounds__(256) void gather_kernel(
    const unsigned char* __restrict__ tf, const int4* __restrict__ offs,
    const float4* __restrict__ wts, float* __restrict__ out) {
  __shared__ float sm[kPTile][261];
  const int b = blockIdx.y;
  // bijective XCD swizzle (m204)
  const int orig = blockIdx.x;
  constexpr int q = kNTiles / 8, r = kNTiles % 8;  // 92, 5
  const int xcd = orig & 7, idx = orig >> 3;
  const int tile = (xcd < r ? xcd * (q + 1) : r * (q + 1) + (xcd - r) * q) + idx;
  const int p0 = tile * kPTile;
  const int tid = threadIdx.x;
  const int w = tid >> 6, l = tid & 63;
  const int l8 = l << 3;  // byte offset of this lane's 4 channels
  const float inv_n = 1.0f / 6.0f;

#pragma unroll 2
  for (int j = 0; j < 8; ++j) {
    const int pl = w * 8 + j;
    const int p = min(p0 + pl, kP - 1);   // clamp tail; out-write guards
    int rec = (b * kP + p) * kN;
    rec = __builtin_amdgcn_readfirstlane(rec);

    int4 o0 = offs[rec + 0], o1 = offs[rec + 1], o2 = offs[rec + 2],
         o3 = offs[rec + 3], o4 = offs[rec + 4], o5 = offs[rec + 5];
    float4 w0 = wts[rec + 0], w1 = wts[rec + 1], w2 = wts[rec + 2],
           w3 = wts[rec + 3], w4 = wts[rec + 4], w5 = wts[rec + 5];

    // ---- issue all 24 loads, no branches ----
#define LD(nm, o) \
    const uint2 nm##x = *(const uint2*)(tf + o.x + l8); \
    const uint2 nm##y = *(const uint2*)(tf + o.y + l8); \
    const uint2 nm##z = *(const uint2*)(tf + o.z + l8); \
    const uint2 nm##w = *(const uint2*)(tf + o.w + l8);
    LD(d0, o0) LD(d1, o1) LD(d2, o2) LD(d3, o3) LD(d4, o4) LD(d5, o5)
#undef LD

    float ax = 0.f, ay = 0.f, az = 0.f, aw = 0.f;
#define ACC(d, wt) \
    ax += wt * bfl(d.x); ay += wt * bfh(d.x); \
    az += wt * bfl(d.y); aw += wt * bfh(d.y);
#define CAM(nm, wv) \
    ACC(nm##x, wv.x) ACC(nm##y, wv.y) ACC(nm##z, wv.z) ACC(nm##w, wv.w)
    CAM(d0, w0) CAM(d1, w1) CAM(d2, w2) CAM(d3, w3) CAM(d4, w4) CAM(d5, w5)
#undef CAM
#undef ACC

    float4 res = make_float4(ax * inv_n, ay * inv_n, az * inv_n, aw * inv_n);
    *(float4*)&sm[pl][l << 2] = res;
  }
  __syncthreads();

  // write: 8 rounds; each instr = 8 c-rows x 32 consecutive p (coalesced)
#pragma unroll
  for (int rd = 0; rd < 8; ++rd) {
    const int cr = rd * 32 + (tid >> 3);
    const int p4 = (tid & 7) * 4;
    const int pg = p0 + p4;
    if (pg < kP) {  // kP%4==0 -> whole float4 chunk valid
      float4 v = make_float4(sm[p4][cr], sm[p4 + 1][cr], sm[p4 + 2][cr],
                             sm[p4 + 3][cr]);
      *(float4*)(out + ((size_t)(b * kC + cr)) * kP + pg) = v;
    }
  }
}

// ---------------- Fallback (R0 kernel) if ws too small -------------------
constexpr int kCChunk = 32;
__global__ __launch_bounds__(256) void ipm_project_kernel(
    const float* __restrict__ feats, const float* __restrict__ intr,
    const float* __restrict__ c2c, float* __restrict__ out) {
  const int p = blockIdx.x * 256 + threadIdx.x;
  const int b = blockIdx.y;
  const int c0 = blockIdx.z * kCChunk;
  const bool inrange = p < kP;
  const int pi = p / kBevW;
  const int pj = p - pi * kBevW;
  const float dx = 75.2f / 188.0f;
  const float dy = 50.4f / 126.0f;
  const float xcar = 0.5f * dx + (float)pi * dx;
  const float ycar = -25.2f + 0.5f * dy + (float)pj * dy;
  int tap[kN][4];
  float tw[kN][4];
  int vmask = 0;
  const float* Kb = intr + (size_t)b * kN * 9;
  const float* Mb = c2c + (size_t)b * kN * 16;
#pragma unroll
  for (int n = 0; n < kN; ++n) {
    const float* M = Mb + n * 16;
    const float* K = Kb + n * 9;
    float Xc = M[0] * xcar + M[1] * ycar + M[3];
    float Yc = M[4] * xcar + M[5] * ycar + M[7];
    float Zc = M[8] * xcar + M[9] * ycar + M[11];
    float u = K[0] * Xc + K[1] * Yc + K[2] * Zc;
    float v = K[3] * Xc + K[4] * Yc + K[5] * Zc;
    float w = K[6] * Xc + K[7] * Yc + K[8] * Zc;
    float z = fmaxf(w, 1e-4f);
    float uf = (u / z) * 0.125f;
    float vf = (v / z) * 0.125f;
    bool valid = inrange && (Zc > 0.1f) && (uf >= 0.0f) && (uf <= 95.0f) &&
                 (vf >= 0.0f) && (vf <= 47.0f);
    if (valid) {
      float un = (uf / 95.0f) * 2.0f - 1.0f;
      float vn = (vf / 47.0f) * 2.0f - 1.0f;
      float ix = (un + 1.0f) * 0.5f * 95.0f;
      float iy = (vn + 1.0f) * 0.5f * 47.0f;
      float x0f = floorf(ix), y0f = floorf(iy);
      float wx1 = ix - x0f, wx0 = 1.0f - wx1;
      float wy1 = iy - y0f, wy0 = 1.0f - wy1;
#pragma unroll
      for (int t = 0; t < 4; ++t) {
        float xf = x0f + (float)(t & 1);
        float yf = y0f + (float)(t >> 1);
        bool inb =
            (xf >= 0.0f) && (xf <= 95.0f) && (yf >= 0.0f) && (yf <= 47.0f);
        int xi = (int)fminf(fmaxf(xf, 0.0f), 95.0f);
        int yi = (int)fminf(fmaxf(yf, 0.0f), 47.0f);
        float wgt = ((t & 1) ? wx1 : wx0) * ((t >> 1) ? wy1 : wy0);
        tap[n][t] = yi * kWf + xi;
        tw[n][t] = inb ? wgt : 0.0f;
      }
      vmask |= (1 << n);
    }
  }
  const float inv_n = 1.0f / 6.0f;
#pragma unroll 4
  for (int k = 0; k < kCChunk; ++k) {
    const int c = c0 + k;
    float acc = 0.0f;
#pragma unroll
    for (int n = 0; n < kN; ++n) {
      if (vmask & (1 << n)) {
        const float* f = feats + ((size_t)(b * kN + n) * kC + c) * kHW;
        acc += f[tap[n][0]] * tw[n][0] + f[tap[n][1]] * tw[n][1] +
               f[tap[n][2]] * tw[n][2] + f[tap[n][3]] * tw[n][3];
      }
    }
    if (inrange) out[((size_t)b * kC + c) * kP + p] = acc * inv_n;
  }
}

}  // namespace

extern "C" void kernel_launch(void* const* d_in, const int* in_sizes, int n_in,
                              void* d_out, int out_size, void* d_ws,
                              size_t ws_size, hipStream_t stream) {
  const float* feats = (const float*)d_in[0];
  const float* intr = (const float*)d_in[1];
  const float* c2c = (const float*)d_in[2];
  float* out = (float*)d_out;

  if (ws_size >= kWsNeeded && d_ws != nullptr) {
    unsigned char* wsb = (unsigned char*)d_ws;
    unsigned short* tf = (unsigned short*)wsb;
    int4* offs = (int4*)(wsb + kImgBytes);
    float4* wtsp = (float4*)(wsb + kImgBytes + kOffsBytes);

    taps_kernel<<<(kB * kP + 255) / 256, 256, 0, stream>>>(intr, c2c, offs,
                                                           wtsp);
    transpose_cvt_kernel<<<dim3(kHW / 32, kC / 64, kB * kN), 256, 0, stream>>>(
        feats, tf);
    gather_kernel<<<dim3(kNTiles, kB), 256, 0, stream>>>(
        (const unsigned char*)tf, offs, wtsp, out);
  } else {
    dim3 grid((kP + 255) / 256, kB, kC / kCChunk);
    ipm_project_kernel<<<grid, dim3(256), 0, stream>>>(feats, intr, c2c, out);
  }
}

// Round 6
// 64.965 us; speedup vs baseline: 1.4631x; 1.0114x over previous
//
#include <hip/hip_runtime.h>

namespace {

constexpr int kBevH = 188, kBevW = 126, kP = kBevH * kBevW;   // 23688
constexpr int kB = 2, kN = 6, kC = 256, kHf = 48, kWf = 96;
constexpr int kHW = kHf * kWf;                                // 4608
constexpr int kPTile = 32;
constexpr int kNTiles = (kP + kPTile - 1) / kPTile;           // 741
constexpr size_t kImgBytes  = (size_t)kB * kN * kHW * kC * 2; // 28.3 MB bf16
constexpr size_t kRecCount  = (size_t)kB * kP * (size_t)kN;   // 284256
constexpr size_t kOffsBytes = kRecCount * 16;
constexpr size_t kWtsBytes  = kRecCount * 16;
constexpr size_t kWsNeeded  = kImgBytes + kOffsBytes + kWtsBytes;

__device__ __forceinline__ unsigned short f2bf(float f) {     // RNE, finite
  union { float f; unsigned u; } a; a.f = f;
  unsigned r = a.u + 0x7fffu + ((a.u >> 16) & 1u);
  return (unsigned short)(r >> 16);
}
__device__ __forceinline__ float bfl(unsigned u) {
  union { unsigned u; float f; } a; a.u = u << 16; return a.f;
}
__device__ __forceinline__ float bfh(unsigned u) {
  union { unsigned u; float f; } a; a.u = u & 0xffff0000u; return a.f;
}

// ---------------- K0: per-(b,p) projection -> tap records ----------------
// ALWAYS writes all 6 records (zero weight/offset for invalid cams) so the
// gather can be branchless.
__global__ __launch_bounds__(256) void taps_kernel(
    const float* __restrict__ intr, const float* __restrict__ c2c,
    int4* __restrict__ offs, float4* __restrict__ wts) {
  const int gid = blockIdx.x * 256 + threadIdx.x;
  if (gid >= kB * kP) return;
  const int b = gid / kP, p = gid - b * kP;
  const int pi = p / kBevW, pj = p - pi * kBevW;
  const float dx = 75.2f / 188.0f, dy = 50.4f / 126.0f;
  const float xcar = 0.5f * dx + (float)pi * dx;
  const float ycar = -25.2f + 0.5f * dy + (float)pj * dy;
  const float* Kb = intr + (size_t)b * kN * 9;
  const float* Mb = c2c + (size_t)b * kN * 16;
#pragma unroll
  for (int n = 0; n < kN; ++n) {
    const float* M = Mb + n * 16;
    const float* K = Kb + n * 9;
    float Xc = M[0] * xcar + M[1] * ycar + M[3];
    float Yc = M[4] * xcar + M[5] * ycar + M[7];
    float Zc = M[8] * xcar + M[9] * ycar + M[11];
    float u = K[0] * Xc + K[1] * Yc + K[2] * Zc;
    float v = K[3] * Xc + K[4] * Yc + K[5] * Zc;
    float w = K[6] * Xc + K[7] * Yc + K[8] * Zc;
    float z = fmaxf(w, 1e-4f);
    float uf = (u / z) * 0.125f;
    float vf = (v / z) * 0.125f;
    bool valid = (Zc > 0.1f) && (uf >= 0.0f) && (uf <= 95.0f) &&
                 (vf >= 0.0f) && (vf <= 47.0f);
    int4 ov = make_int4(0, 0, 0, 0);
    float4 wv = make_float4(0.f, 0.f, 0.f, 0.f);
    if (valid) {
      // reproduce reference op order (norm round-trip)
      float un = (uf / 95.0f) * 2.0f - 1.0f;
      float vn = (vf / 47.0f) * 2.0f - 1.0f;
      float ix = (un + 1.0f) * 0.5f * 95.0f;
      float iy = (vn + 1.0f) * 0.5f * 47.0f;
      float x0f = floorf(ix), y0f = floorf(iy);
      float wx1 = ix - x0f, wx0 = 1.0f - wx1;
      float wy1 = iy - y0f, wy0 = 1.0f - wy1;
      int o[4]; float wt[4];
#pragma unroll
      for (int t = 0; t < 4; ++t) {
        float xf = x0f + (float)(t & 1);
        float yf = y0f + (float)(t >> 1);
        bool inb = (xf >= 0.0f) && (xf <= 95.0f) && (yf >= 0.0f) &&
                   (yf <= 47.0f);
        int xi = (int)fminf(fmaxf(xf, 0.0f), 95.0f);
        int yi = (int)fminf(fmaxf(yf, 0.0f), 47.0f);
        float wgt = ((t & 1) ? wx1 : wx0) * ((t >> 1) ? wy1 : wy0);
        o[t] = (((b * kN + n) * kHW) + yi * kWf + xi) * (kC * 2);  // byte off
        wt[t] = inb ? wgt : 0.0f;
      }
      ov = make_int4(o[0], o[1], o[2], o[3]);
      wv = make_float4(wt[0], wt[1], wt[2], wt[3]);
    }
    offs[(size_t)gid * kN + n] = ov;
    wts[(size_t)gid * kN + n] = wv;
  }
}

// ------------- K1: feats f32 [B,N,C,H,W] -> bf16 [B,N,HW,C] --------------
__global__ __launch_bounds__(256) void transpose_cvt_kernel(
    const float* __restrict__ src, unsigned short* __restrict__ dst) {
  __shared__ float tile[64][33];
  const int m = blockIdx.z;
  const int hw0 = blockIdx.x * 32;
  const int c0 = blockIdx.y * 64;
  const float* s = src + (size_t)m * kC * kHW;
  unsigned short* d = dst + (size_t)m * kHW * kC;
  const int hw = threadIdx.x & 31, cl = threadIdx.x >> 5;
#pragma unroll
  for (int k = 0; k < 8; ++k)
    tile[cl + 8 * k][hw] = s[(size_t)(c0 + cl + 8 * k) * kHW + hw0 + hw];
  __syncthreads();
  const int cp = threadIdx.x & 31, hwl = threadIdx.x >> 5;
#pragma unroll
  for (int k = 0; k < 4; ++k) {
    const int h = hwl + 8 * k;
    ushort2 uv;
    uv.x = f2bf(tile[2 * cp][h]);
    uv.y = f2bf(tile[2 * cp + 1][h]);
    *(ushort2*)(d + (size_t)(hw0 + h) * kC + c0 + 2 * cp) = uv;
  }
}

// ------------- K2: branchless batched gather, 8 waves/block ---------------
// Block = 8 waves (512 thr), 32 p, all 256 c. Wave w owns p = p0+4w..p0+4w+3.
// Per p: 24 INDEPENDENT uint2 loads issued back-to-back (deep MLP).
// Records are wave-uniform -> readfirstlane -> s_load path.
// LDS 33.4KB -> 4 blocks/CU x 8 waves = 32 waves/CU (full TLP).
__global__ __launch_bounds__(512) void gather_kernel(
    const unsigned char* __restrict__ tf, const int4* __restrict__ offs,
    const float4* __restrict__ wts, float* __restrict__ out) {
  __shared__ float sm[kPTile][261];
  const int b = blockIdx.y;
  // bijective XCD swizzle (m204)
  const int orig = blockIdx.x;
  constexpr int q = kNTiles / 8, r = kNTiles % 8;  // 92, 5
  const int xcd = orig & 7, idx = orig >> 3;
  const int tile = (xcd < r ? xcd * (q + 1) : r * (q + 1) + (xcd - r) * q) + idx;
  const int p0 = tile * kPTile;
  const int tid = threadIdx.x;
  const int w = tid >> 6, l = tid & 63;
  const int l8 = l << 3;  // byte offset of this lane's 4 channels
  const float inv_n = 1.0f / 6.0f;

#pragma unroll 2
  for (int j = 0; j < 4; ++j) {
    const int pl = w * 4 + j;
    const int p = min(p0 + pl, kP - 1);   // clamp tail; out-write guards
    int rec = (b * kP + p) * kN;
    rec = __builtin_amdgcn_readfirstlane(rec);

    int4 o0 = offs[rec + 0], o1 = offs[rec + 1], o2 = offs[rec + 2],
         o3 = offs[rec + 3], o4 = offs[rec + 4], o5 = offs[rec + 5];
    float4 w0 = wts[rec + 0], w1 = wts[rec + 1], w2 = wts[rec + 2],
           w3 = wts[rec + 3], w4 = wts[rec + 4], w5 = wts[rec + 5];

    // ---- issue all 24 loads, no branches ----
#define LD(nm, o) \
    const uint2 nm##x = *(const uint2*)(tf + o.x + l8); \
    const uint2 nm##y = *(const uint2*)(tf + o.y + l8); \
    const uint2 nm##z = *(const uint2*)(tf + o.z + l8); \
    const uint2 nm##w = *(const uint2*)(tf + o.w + l8);
    LD(d0, o0) LD(d1, o1) LD(d2, o2) LD(d3, o3) LD(d4, o4) LD(d5, o5)
#undef LD

    float ax = 0.f, ay = 0.f, az = 0.f, aw = 0.f;
#define ACC(d, wt) \
    ax += wt * bfl(d.x); ay += wt * bfh(d.x); \
    az += wt * bfl(d.y); aw += wt * bfh(d.y);
#define CAM(nm, wv) \
    ACC(nm##x, wv.x) ACC(nm##y, wv.y) ACC(nm##z, wv.z) ACC(nm##w, wv.w)
    CAM(d0, w0) CAM(d1, w1) CAM(d2, w2) CAM(d3, w3) CAM(d4, w4) CAM(d5, w5)
#undef CAM
#undef ACC

    float4 res = make_float4(ax * inv_n, ay * inv_n, az * inv_n, aw * inv_n);
    *(float4*)&sm[pl][l << 2] = res;
  }
  __syncthreads();

  // write: 4 rounds; each round = 64 c-rows x 32 consecutive p (coalesced)
#pragma unroll
  for (int rd = 0; rd < 4; ++rd) {
    const int cr = rd * 64 + (tid >> 3);
    const int p4 = (tid & 7) * 4;
    const int pg = p0 + p4;
    if (pg < kP) {  // kP%4==0 -> whole float4 chunk valid
      float4 v = make_float4(sm[p4][cr], sm[p4 + 1][cr], sm[p4 + 2][cr],
                             sm[p4 + 3][cr]);
      *(float4*)(out + ((size_t)(b * kC + cr)) * kP + pg) = v;
    }
  }
}

// ---------------- Fallback (R0 kernel) if ws too small -------------------
constexpr int kCChunk = 32;
__global__ __launch_bounds__(256) void ipm_project_kernel(
    const float* __restrict__ feats, const float* __restrict__ intr,
    const float* __restrict__ c2c, float* __restrict__ out) {
  const int p = blockIdx.x * 256 + threadIdx.x;
  const int b = blockIdx.y;
  const int c0 = blockIdx.z * kCChunk;
  const bool inrange = p < kP;
  const int pi = p / kBevW;
  const int pj = p - pi * kBevW;
  const float dx = 75.2f / 188.0f;
  const float dy = 50.4f / 126.0f;
  const float xcar = 0.5f * dx + (float)pi * dx;
  const float ycar = -25.2f + 0.5f * dy + (float)pj * dy;
  int tap[kN][4];
  float tw[kN][4];
  int vmask = 0;
  const float* Kb = intr + (size_t)b * kN * 9;
  const float* Mb = c2c + (size_t)b * kN * 16;
#pragma unroll
  for (int n = 0; n < kN; ++n) {
    const float* M = Mb + n * 16;
    const float* K = Kb + n * 9;
    float Xc = M[0] * xcar + M[1] * ycar + M[3];
    float Yc = M[4] * xcar + M[5] * ycar + M[7];
    float Zc = M[8] * xcar + M[9] * ycar + M[11];
    float u = K[0] * Xc + K[1] * Yc + K[2] * Zc;
    float v = K[3] * Xc + K[4] * Yc + K[5] * Zc;
    float w = K[6] * Xc + K[7] * Yc + K[8] * Zc;
    float z = fmaxf(w, 1e-4f);
    float uf = (u / z) * 0.125f;
    float vf = (v / z) * 0.125f;
    bool valid = inrange && (Zc > 0.1f) && (uf >= 0.0f) && (uf <= 95.0f) &&
                 (vf >= 0.0f) && (vf <= 47.0f);
    if (valid) {
      float un = (uf / 95.0f) * 2.0f - 1.0f;
      float vn = (vf / 47.0f) * 2.0f - 1.0f;
      float ix = (un + 1.0f) * 0.5f * 95.0f;
      float iy = (vn + 1.0f) * 0.5f * 47.0f;
      float x0f = floorf(ix), y0f = floorf(iy);
      float wx1 = ix - x0f, wx0 = 1.0f - wx1;
      float wy1 = iy - y0f, wy0 = 1.0f - wy1;
#pragma unroll
      for (int t = 0; t < 4; ++t) {
        float xf = x0f + (float)(t & 1);
        float yf = y0f + (float)(t >> 1);
        bool inb =
            (xf >= 0.0f) && (xf <= 95.0f) && (yf >= 0.0f) && (yf <= 47.0f);
        int xi = (int)fminf(fmaxf(xf, 0.0f), 95.0f);
        int yi = (int)fminf(fmaxf(yf, 0.0f), 47.0f);
        float wgt = ((t & 1) ? wx1 : wx0) * ((t >> 1) ? wy1 : wy0);
        tap[n][t] = yi * kWf + xi;
        tw[n][t] = inb ? wgt : 0.0f;
      }
      vmask |= (1 << n);
    }
  }
  const float inv_n = 1.0f / 6.0f;
#pragma unroll 4
  for (int k = 0; k < kCChunk; ++k) {
    const int c = c0 + k;
    float acc = 0.0f;
#pragma unroll
    for (int n = 0; n < kN; ++n) {
      if (vmask & (1 << n)) {
        const float* f = feats + ((size_t)(b * kN + n) * kC + c) * kHW;
        acc += f[tap[n][0]] * tw[n][0] + f[tap[n][1]] * tw[n][1] +
               f[tap[n][2]] * tw[n][2] + f[tap[n][3]] * tw[n][3];
      }
    }
    if (inrange) out[((size_t)b * kC + c) * kP + p] = acc * inv_n;
  }
}

}  // namespace

extern "C" void kernel_launch(void* const* d_in, const int* in_sizes, int n_in,
                              void* d_out, int out_size, void* d_ws,
                              size_t ws_size, hipStream_t stream) {
  const float* feats = (const float*)d_in[0];
  const float* intr = (const float*)d_in[1];
  const float* c2c = (const float*)d_in[2];
  float* out = (float*)d_out;

  if (ws_size >= kWsNeeded && d_ws != nullptr) {
    unsigned char* wsb = (unsigned char*)d_ws;
    unsigned short* tf = (unsigned short*)wsb;
    int4* offs = (int4*)(wsb + kImgBytes);
    float4* wtsp = (float4*)(wsb + kImgBytes + kOffsBytes);

    taps_kernel<<<(kB * kP + 255) / 256, 256, 0, stream>>>(intr, c2c, offs,
                                                           wtsp);
    transpose_cvt_kernel<<<dim3(kHW / 32, kC / 64, kB * kN), 256, 0, stream>>>(
        feats, tf);
    gather_kernel<<<dim3(kNTiles, kB), 512, 0, stream>>>(
        (const unsigned char*)tf, offs, wtsp, out);
  } else {
    dim3 grid((kP + 255) / 256, kB, kC / kCChunk);
    ipm_project_kernel<<<grid, dim3(256), 0, stream>>>(feats, intr, c2c, out);
  }
}

// Round 7
// 54.291 us; speedup vs baseline: 1.7508x; 1.1966x over previous
//
#include <hip/hip_runtime.h>

namespace {

constexpr int kBevH = 188, kBevW = 126, kP = kBevH * kBevW;   // 23688
constexpr int kB = 2, kN = 6, kC = 256, kHf = 48, kWf = 96;
constexpr int kHW = kHf * kWf;                                // 4608
constexpr int kPixBytes = kC * 2;                             // 512 B bf16
constexpr int kPTile = 32;
constexpr int kNTiles = (kP + kPTile - 1) / kPTile;           // 741
constexpr size_t kImgBytes  = (size_t)kB * kN * kHW * kC * 2; // 28.3 MB bf16
constexpr size_t kRecCount  = (size_t)kB * kP * (size_t)kN;   // 284256
constexpr size_t kOffsBytes = kRecCount * 8;                  // int2
constexpr size_t kWtsBytes  = kRecCount * 16;                 // float4
constexpr size_t kWsNeeded  = kImgBytes + kOffsBytes + kWtsBytes;

__device__ __forceinline__ unsigned short f2bf(float f) {     // RNE, finite
  union { float f; unsigned u; } a; a.f = f;
  unsigned r = a.u + 0x7fffu + ((a.u >> 16) & 1u);
  return (unsigned short)(r >> 16);
}
__device__ __forceinline__ float bfl(unsigned u) {
  union { unsigned u; float f; } a; a.u = u << 16; return a.f;
}
__device__ __forceinline__ float bfh(unsigned u) {
  union { unsigned u; float f; } a; a.u = u & 0xffff0000u; return a.f;
}

// ---------------- K0: per-(b,p) projection -> paired tap records ---------
// Per cam: two byte offsets (y0-row pair base, y1-row pair base), each the
// start of a contiguous 1KB [x][x+1] pixel-vector pair, plus 4 half-weights
// (h0*wy0, h1*wy0, h0*wy1, h1*wy1). Boundary taps are clamped into the image
// with their weight moved/zeroed, so every load reads real pixel data.
__global__ __launch_bounds__(256) void taps_kernel(
    const float* __restrict__ intr, const float* __restrict__ c2c,
    int2* __restrict__ offs, float4* __restrict__ wts) {
  const int gid = blockIdx.x * 256 + threadIdx.x;
  if (gid >= kB * kP) return;
  const int b = gid / kP, p = gid - b * kP;
  const int pi = p / kBevW, pj = p - pi * kBevW;
  const float dx = 75.2f / 188.0f, dy = 50.4f / 126.0f;
  const float xcar = 0.5f * dx + (float)pi * dx;
  const float ycar = -25.2f + 0.5f * dy + (float)pj * dy;
  const float* Kb = intr + (size_t)b * kN * 9;
  const float* Mb = c2c + (size_t)b * kN * 16;
#pragma unroll
  for (int n = 0; n < kN; ++n) {
    const float* M = Mb + n * 16;
    const float* K = Kb + n * 9;
    float Xc = M[0] * xcar + M[1] * ycar + M[3];
    float Yc = M[4] * xcar + M[5] * ycar + M[7];
    float Zc = M[8] * xcar + M[9] * ycar + M[11];
    float u = K[0] * Xc + K[1] * Yc + K[2] * Zc;
    float v = K[3] * Xc + K[4] * Yc + K[5] * Zc;
    float w = K[6] * Xc + K[7] * Yc + K[8] * Zc;
    float z = fmaxf(w, 1e-4f);
    float uf = (u / z) * 0.125f;
    float vf = (v / z) * 0.125f;
    bool valid = (Zc > 0.1f) && (uf >= 0.0f) && (uf <= 95.0f) &&
                 (vf >= 0.0f) && (vf <= 47.0f);
    int2 ov = make_int2(0, 0);
    float4 wv = make_float4(0.f, 0.f, 0.f, 0.f);
    if (valid) {
      // reproduce reference op order (norm round-trip)
      float un = (uf / 95.0f) * 2.0f - 1.0f;
      float vn = (vf / 47.0f) * 2.0f - 1.0f;
      float ix = (un + 1.0f) * 0.5f * 95.0f;
      float iy = (vn + 1.0f) * 0.5f * 47.0f;
      float x0f = floorf(ix), y0f = floorf(iy);
      float wx1 = ix - x0f, wx0 = 1.0f - wx1;
      float wy1 = iy - y0f, wy0 = 1.0f - wy1;
      int x0i = (int)x0f;              // in [0,95]
      int y0i = (int)y0f;              // in [0,47]
      int xb = min(x0i, 94);           // pair base column
      // half-weights: normally (wx0,wx1); at x0=95 pair is (94,95) -> (0,wx0)
      float h0 = (x0i <= 94) ? wx0 : 0.0f;
      float h1 = (x0i <= 94) ? wx1 : wx0;
      int y1i = min(y0i + 1, 47);      // wy1==0 when clamped (iy==47.0)
      const int pix = (b * kN + n) * kHW;
      ov.x = (pix + y0i * kWf + xb) * kPixBytes;
      ov.y = (pix + y1i * kWf + xb) * kPixBytes;
      wv = make_float4(h0 * wy0, h1 * wy0, h0 * wy1, h1 * wy1);
    }
    offs[(size_t)gid * kN + n] = ov;
    wts[(size_t)gid * kN + n] = wv;
  }
}

// ------------- K1: feats f32 [B,N,C,H,W] -> bf16 [B,N,HW,C] --------------
__global__ __launch_bounds__(256) void transpose_cvt_kernel(
    const float* __restrict__ src, unsigned short* __restrict__ dst) {
  __shared__ float tile[64][33];
  const int m = blockIdx.z;
  const int hw0 = blockIdx.x * 32;
  const int c0 = blockIdx.y * 64;
  const float* s = src + (size_t)m * kC * kHW;
  unsigned short* d = dst + (size_t)m * kHW * kC;
  const int hw = threadIdx.x & 31, cl = threadIdx.x >> 5;
#pragma unroll
  for (int k = 0; k < 8; ++k)
    tile[cl + 8 * k][hw] = s[(size_t)(c0 + cl + 8 * k) * kHW + hw0 + hw];
  __syncthreads();
  const int cp = threadIdx.x & 31, hwl = threadIdx.x >> 5;
#pragma unroll
  for (int k = 0; k < 4; ++k) {
    const int h = hwl + 8 * k;
    ushort2 uv;
    uv.x = f2bf(tile[2 * cp][h]);
    uv.y = f2bf(tile[2 * cp + 1][h]);
    *(ushort2*)(d + (size_t)(hw0 + h) * kC + c0 + 2 * cp) = uv;
  }
}

// ------------- K2: paired dwordx4 gather, half-wave x-split --------------
// Block = 8 waves (512 thr), 32 p, all 256 c. Wave w owns p = p0+4w..+3.
// Per (p,cam): 2 global_load_dwordx4 spanning the 1KB (x0,x0+1) pixel pair;
// lanes<32 hold x0's channels, lanes>=32 hold x0+1's. Half-weights select
// per lane; one shfl_xor(32) pass sums the halves at the end.
__global__ __launch_bounds__(512) void gather_kernel(
    const unsigned char* __restrict__ tf, const int2* __restrict__ offs,
    const float4* __restrict__ wts, float* __restrict__ out) {
  __shared__ float sm[kPTile][261];
  const int b = blockIdx.y;
  // bijective XCD swizzle (m204)
  const int orig = blockIdx.x;
  constexpr int q = kNTiles / 8, r = kNTiles % 8;  // 92, 5
  const int xcd = orig & 7, idx = orig >> 3;
  const int tile = (xcd < r ? xcd * (q + 1) : r * (q + 1) + (xcd - r) * q) + idx;
  const int p0 = tile * kPTile;
  const int tid = threadIdx.x;
  const int w = tid >> 6, l = tid & 63;
  const int half = l >> 5;
  const int l16 = l << 4;            // byte offset within the 1KB pair
  const float inv_n = 1.0f / 6.0f;

#pragma unroll 2
  for (int j = 0; j < 4; ++j) {
    const int pl = w * 4 + j;
    const int p = min(p0 + pl, kP - 1);   // clamp tail; out-write guards
    int rec = (b * kP + p) * kN;
    rec = __builtin_amdgcn_readfirstlane(rec);

    const int2 o0 = offs[rec + 0], o1 = offs[rec + 1], o2 = offs[rec + 2],
               o3 = offs[rec + 3], o4 = offs[rec + 4], o5 = offs[rec + 5];
    const float4 w0 = wts[rec + 0], w1 = wts[rec + 1], w2 = wts[rec + 2],
                 w3 = wts[rec + 3], w4 = wts[rec + 4], w5 = wts[rec + 5];

    // ---- issue all 12 dwordx4 loads back-to-back ----
#define LD(nm, o) \
    const uint4 nm##a = *(const uint4*)(tf + (size_t)o.x + l16); \
    const uint4 nm##b = *(const uint4*)(tf + (size_t)o.y + l16);
    LD(d0, o0) LD(d1, o1) LD(d2, o2) LD(d3, o3) LD(d4, o4) LD(d5, o5)
#undef LD

    float a0 = 0.f, a1 = 0.f, a2 = 0.f, a3 = 0.f,
          a4 = 0.f, a5 = 0.f, a6 = 0.f, a7 = 0.f;
#define CAM(nm, wv) { \
    const float wA = half ? wv.y : wv.x; \
    const float wB = half ? wv.w : wv.z; \
    a0 += wA * bfl(nm##a.x) + wB * bfl(nm##b.x); \
    a1 += wA * bfh(nm##a.x) + wB * bfh(nm##b.x); \
    a2 += wA * bfl(nm##a.y) + wB * bfl(nm##b.y); \
    a3 += wA * bfh(nm##a.y) + wB * bfh(nm##b.y); \
    a4 += wA * bfl(nm##a.z) + wB * bfl(nm##b.z); \
    a5 += wA * bfh(nm##a.z) + wB * bfh(nm##b.z); \
    a6 += wA * bfl(nm##a.w) + wB * bfl(nm##b.w); \
    a7 += wA * bfh(nm##a.w) + wB * bfh(nm##b.w); }
    CAM(d0, w0) CAM(d1, w1) CAM(d2, w2) CAM(d3, w3) CAM(d4, w4) CAM(d5, w5)
#undef CAM

    // sum the two x-halves (lane l <-> l+32); both halves end with the total
    a0 += __shfl_xor(a0, 32); a1 += __shfl_xor(a1, 32);
    a2 += __shfl_xor(a2, 32); a3 += __shfl_xor(a3, 32);
    a4 += __shfl_xor(a4, 32); a5 += __shfl_xor(a5, 32);
    a6 += __shfl_xor(a6, 32); a7 += __shfl_xor(a7, 32);

    // lane handles channels 8*(l&31)..+7; half0 stores ch+0..3, half1 +4..7
    const int cbase = ((l & 31) << 3) + (half << 2);
    float4 vs = half ? make_float4(a4, a5, a6, a7)
                     : make_float4(a0, a1, a2, a3);
    vs.x *= inv_n; vs.y *= inv_n; vs.z *= inv_n; vs.w *= inv_n;
    *(float4*)&sm[pl][cbase] = vs;
  }
  __syncthreads();

  // write: 4 rounds; each round = 64 c-rows x 32 consecutive p (coalesced)
#pragma unroll
  for (int rd = 0; rd < 4; ++rd) {
    const int cr = rd * 64 + (tid >> 3);
    const int p4 = (tid & 7) * 4;
    const int pg = p0 + p4;
    if (pg < kP) {  // kP%4==0 -> whole float4 chunk valid
      float4 v = make_float4(sm[p4][cr], sm[p4 + 1][cr], sm[p4 + 2][cr],
                             sm[p4 + 3][cr]);
      *(float4*)(out + ((size_t)(b * kC + cr)) * kP + pg) = v;
    }
  }
}

// ---------------- Fallback (R0 kernel) if ws too small -------------------
constexpr int kCChunk = 32;
__global__ __launch_bounds__(256) void ipm_project_kernel(
    const float* __restrict__ feats, const float* __restrict__ intr,
    const float* __restrict__ c2c, float* __restrict__ out) {
  const int p = blockIdx.x * 256 + threadIdx.x;
  const int b = blockIdx.y;
  const int c0 = blockIdx.z * kCChunk;
  const bool inrange = p < kP;
  const int pi = p / kBevW;
  const int pj = p - pi * kBevW;
  const float dx = 75.2f / 188.0f;
  const float dy = 50.4f / 126.0f;
  const float xcar = 0.5f * dx + (float)pi * dx;
  const float ycar = -25.2f + 0.5f * dy + (float)pj * dy;
  int tap[kN][4];
  float tw[kN][4];
  int vmask = 0;
  const float* Kb = intr + (size_t)b * kN * 9;
  const float* Mb = c2c + (size_t)b * kN * 16;
#pragma unroll
  for (int n = 0; n < kN; ++n) {
    const float* M = Mb + n * 16;
    const float* K = Kb + n * 9;
    float Xc = M[0] * xcar + M[1] * ycar + M[3];
    float Yc = M[4] * xcar + M[5] * ycar + M[7];
    float Zc = M[8] * xcar + M[9] * ycar + M[11];
    float u = K[0] * Xc + K[1] * Yc + K[2] * Zc;
    float v = K[3] * Xc + K[4] * Yc + K[5] * Zc;
    float w = K[6] * Xc + K[7] * Yc + K[8] * Zc;
    float z = fmaxf(w, 1e-4f);
    float uf = (u / z) * 0.125f;
    float vf = (v / z) * 0.125f;
    bool valid = inrange && (Zc > 0.1f) && (uf >= 0.0f) && (uf <= 95.0f) &&
                 (vf >= 0.0f) && (vf <= 47.0f);
    if (valid) {
      float un = (uf / 95.0f) * 2.0f - 1.0f;
      float vn = (vf / 47.0f) * 2.0f - 1.0f;
      float ix = (un + 1.0f) * 0.5f * 95.0f;
      float iy = (vn + 1.0f) * 0.5f * 47.0f;
      float x0f = floorf(ix), y0f = floorf(iy);
      float wx1 = ix - x0f, wx0 = 1.0f - wx1;
      float wy1 = iy - y0f, wy0 = 1.0f - wy1;
#pragma unroll
      for (int t = 0; t < 4; ++t) {
        float xf = x0f + (float)(t & 1);
        float yf = y0f + (float)(t >> 1);
        bool inb =
            (xf >= 0.0f) && (xf <= 95.0f) && (yf >= 0.0f) && (yf <= 47.0f);
        int xi = (int)fminf(fmaxf(xf, 0.0f), 95.0f);
        int yi = (int)fminf(fmaxf(yf, 0.0f), 47.0f);
        float wgt = ((t & 1) ? wx1 : wx0) * ((t >> 1) ? wy1 : wy0);
        tap[n][t] = yi * kWf + xi;
        tw[n][t] = inb ? wgt : 0.0f;
      }
      vmask |= (1 << n);
    }
  }
  const float inv_n = 1.0f / 6.0f;
#pragma unroll 4
  for (int k = 0; k < kCChunk; ++k) {
    const int c = c0 + k;
    float acc = 0.0f;
#pragma unroll
    for (int n = 0; n < kN; ++n) {
      if (vmask & (1 << n)) {
        const float* f = feats + ((size_t)(b * kN + n) * kC + c) * kHW;
        acc += f[tap[n][0]] * tw[n][0] + f[tap[n][1]] * tw[n][1] +
               f[tap[n][2]] * tw[n][2] + f[tap[n][3]] * tw[n][3];
      }
    }
    if (inrange) out[((size_t)b * kC + c) * kP + p] = acc * inv_n;
  }
}

}  // namespace

extern "C" void kernel_launch(void* const* d_in, const int* in_sizes, int n_in,
                              void* d_out, int out_size, void* d_ws,
                              size_t ws_size, hipStream_t stream) {
  const float* feats = (const float*)d_in[0];
  const float* intr = (const float*)d_in[1];
  const float* c2c = (const float*)d_in[2];
  float* out = (float*)d_out;

  if (ws_size >= kWsNeeded && d_ws != nullptr) {
    unsigned char* wsb = (unsigned char*)d_ws;
    unsigned short* tf = (unsigned short*)wsb;
    int2* offs = (int2*)(wsb + kImgBytes);
    float4* wtsp = (float4*)(wsb + kImgBytes + kOffsBytes);

    taps_kernel<<<(kB * kP + 255) / 256, 256, 0, stream>>>(intr, c2c, offs,
                                                           wtsp);
    transpose_cvt_kernel<<<dim3(kHW / 32, kC / 64, kB * kN), 256, 0, stream>>>(
        feats, tf);
    gather_kernel<<<dim3(kNTiles, kB), 512, 0, stream>>>(
        (const unsigned char*)tf, offs, wtsp, out);
  } else {
    dim3 grid((kP + 255) / 256, kB, kC / kCChunk);
    ipm_project_kernel<<<grid, dim3(256), 0, stream>>>(feats, intr, c2c, out);
  }
}

// Round 9
// 53.030 us; speedup vs baseline: 1.7924x; 1.0238x over previous
//
#include <hip/hip_runtime.h>

namespace {

constexpr int kBevH = 188, kBevW = 126, kP = kBevH * kBevW;   // 23688
constexpr int kB = 2, kN = 6, kC = 256, kHf = 48, kWf = 96;
constexpr int kHW = kHf * kWf;                                // 4608
constexpr int kPixBytes = kC * 2;                             // 512 B bf16
constexpr int kPTile = 32;
constexpr int kNTiles = (kP + kPTile - 1) / kPTile;           // 741
constexpr size_t kImgBytes  = (size_t)kB * kN * kHW * kC * 2; // 28.3 MB bf16
constexpr size_t kRecCount  = (size_t)kB * kP * (size_t)kN;   // 284256
constexpr size_t kOffsBytes = kRecCount * 8;                  // int2
constexpr size_t kWtsBytes  = kRecCount * 16;                 // float4
constexpr size_t kCntBytes  = (size_t)kB * kP * 4;
constexpr size_t kWsNeeded  = kImgBytes + kOffsBytes + kWtsBytes + kCntBytes;

__device__ __forceinline__ unsigned short f2bf(float f) {     // RNE, finite
  union { float f; unsigned u; } a; a.f = f;
  unsigned r = a.u + 0x7fffu + ((a.u >> 16) & 1u);
  return (unsigned short)(r >> 16);
}
__device__ __forceinline__ float bfl(unsigned u) {
  union { unsigned u; float f; } a; a.u = u << 16; return a.f;
}
__device__ __forceinline__ float bfh(unsigned u) {
  union { unsigned u; float f; } a; a.u = u & 0xffff0000u; return a.f;
}

// ---------------- K0: projection -> COMPACTED paired tap records ---------
// Valid cams are compacted to slots [0, cnt) of the p's 6 record slots.
// Record: int2 (y0-row pair base, y1-row pair base byte offsets) + float4
// half-weights (h0*wy0, h1*wy0, h0*wy1, h1*wy1). Boundary taps clamped
// into the image with weights remapped, so every load reads real pixels.
__global__ __launch_bounds__(256) void taps_kernel(
    const float* __restrict__ intr, const float* __restrict__ c2c,
    int2* __restrict__ offs, float4* __restrict__ wts,
    int* __restrict__ cnts) {
  const int gid = blockIdx.x * 256 + threadIdx.x;
  if (gid >= kB * kP) return;
  const int b = gid / kP, p = gid - b * kP;
  const int pi = p / kBevW, pj = p - pi * kBevW;
  const float dx = 75.2f / 188.0f, dy = 50.4f / 126.0f;
  const float xcar = 0.5f * dx + (float)pi * dx;
  const float ycar = -25.2f + 0.5f * dy + (float)pj * dy;
  const float* Kb = intr + (size_t)b * kN * 9;
  const float* Mb = c2c + (size_t)b * kN * 16;
  int cnt = 0;
#pragma unroll
  for (int n = 0; n < kN; ++n) {
    const float* M = Mb + n * 16;
    const float* K = Kb + n * 9;
    float Xc = M[0] * xcar + M[1] * ycar + M[3];
    float Yc = M[4] * xcar + M[5] * ycar + M[7];
    float Zc = M[8] * xcar + M[9] * ycar + M[11];
    float u = K[0] * Xc + K[1] * Yc + K[2] * Zc;
    float v = K[3] * Xc + K[4] * Yc + K[5] * Zc;
    float w = K[6] * Xc + K[7] * Yc + K[8] * Zc;
    float z = fmaxf(w, 1e-4f);
    float uf = (u / z) * 0.125f;
    float vf = (v / z) * 0.125f;
    bool valid = (Zc > 0.1f) && (uf >= 0.0f) && (uf <= 95.0f) &&
                 (vf >= 0.0f) && (vf <= 47.0f);
    if (valid) {
      // reproduce reference op order (norm round-trip)
      float un = (uf / 95.0f) * 2.0f - 1.0f;
      float vn = (vf / 47.0f) * 2.0f - 1.0f;
      float ix = (un + 1.0f) * 0.5f * 95.0f;
      float iy = (vn + 1.0f) * 0.5f * 47.0f;
      float x0f = floorf(ix), y0f = floorf(iy);
      float wx1 = ix - x0f, wx0 = 1.0f - wx1;
      float wy1 = iy - y0f, wy0 = 1.0f - wy1;
      int x0i = (int)x0f;              // in [0,95]
      int y0i = (int)y0f;              // in [0,47]
      int xb = min(x0i, 94);           // pair base column
      float h0 = (x0i <= 94) ? wx0 : 0.0f;
      float h1 = (x0i <= 94) ? wx1 : wx0;
      int y1i = min(y0i + 1, 47);      // wy1==0 when clamped (iy==47.0)
      const int pix = (b * kN + n) * kHW;
      int2 ov;
      ov.x = (pix + y0i * kWf + xb) * kPixBytes;
      ov.y = (pix + y1i * kWf + xb) * kPixBytes;
      offs[(size_t)gid * kN + cnt] = ov;
      wts[(size_t)gid * kN + cnt] =
          make_float4(h0 * wy0, h1 * wy0, h0 * wy1, h1 * wy1);
      ++cnt;
    }
  }
  cnts[gid] = cnt;
}

// ------------- K1: feats f32 [B,N,C,H,W] -> bf16 [B,N,HW,C] --------------
__global__ __launch_bounds__(256) void transpose_cvt_kernel(
    const float* __restrict__ src, unsigned short* __restrict__ dst) {
  __shared__ float tile[64][33];
  const int m = blockIdx.z;
  const int hw0 = blockIdx.x * 32;
  const int c0 = blockIdx.y * 64;
  const float* s = src + (size_t)m * kC * kHW;
  unsigned short* d = dst + (size_t)m * kHW * kC;
  const int hw = threadIdx.x & 31, cl = threadIdx.x >> 5;
#pragma unroll
  for (int k = 0; k < 8; ++k)
    tile[cl + 8 * k][hw] = s[(size_t)(c0 + cl + 8 * k) * kHW + hw0 + hw];
  __syncthreads();
  const int cp = threadIdx.x & 31, hwl = threadIdx.x >> 5;
#pragma unroll
  for (int k = 0; k < 4; ++k) {
    const int h = hwl + 8 * k;
    ushort2 uv;
    uv.x = f2bf(tile[2 * cp][h]);
    uv.y = f2bf(tile[2 * cp + 1][h]);
    *(ushort2*)(d + (size_t)(hw0 + h) * kC + c0 + 2 * cp) = uv;
  }
}

// ------------- K2: compacted paired-dwordx4 gather -----------------------
// Block = 8 waves (512 thr), 32 p, all 256 c. Wave w owns p = p0+4w..+3;
// for fixed j the whole wave works one p -> cnt is wave-uniform (scalar
// loop, zero divergence). Per valid cam: 2 dwordx4 spanning the 1KB
// (x0,x0+1) pixel pair; lanes<32 = x0 channels, lanes>=32 = x0+1.
// One shfl_xor(32) pass sums the halves.
__global__ __launch_bounds__(512) void gather_kernel(
    const unsigned char* __restrict__ tf, const int2* __restrict__ offs,
    const float4* __restrict__ wts, const int* __restrict__ cnts,
    float* __restrict__ out) {
  __shared__ float sm[kPTile][261];
  const int b = blockIdx.y;
  // bijective XCD swizzle (m204)
  const int orig = blockIdx.x;
  constexpr int q = kNTiles / 8, r = kNTiles % 8;  // 92, 5
  const int xcd = orig & 7, idx = orig >> 3;
  const int tile = (xcd < r ? xcd * (q + 1) : r * (q + 1) + (xcd - r) * q) + idx;
  const int p0 = tile * kPTile;
  const int tid = threadIdx.x;
  const int w = tid >> 6, l = tid & 63;
  const int half = l >> 5;
  const int l16 = l << 4;            // byte offset within the 1KB pair
  const float inv_n = 1.0f / 6.0f;

#pragma unroll
  for (int j = 0; j < 4; ++j) {
    const int pl = w * 4 + j;
    const int p = min(p0 + pl, kP - 1);   // clamp tail; out-write guards
    const int pr = b * kP + p;            // wave-uniform
    const int rec = __builtin_amdgcn_readfirstlane(pr * kN);
    const int cnt = __builtin_amdgcn_readfirstlane(cnts[pr]);

    float a0 = 0.f, a1 = 0.f, a2 = 0.f, a3 = 0.f,
          a4 = 0.f, a5 = 0.f, a6 = 0.f, a7 = 0.f;

#define CAM(da, db, wv) { \
    const float selA = half ? wv.y : wv.x; \
    const float selB = half ? wv.w : wv.z; \
    a0 += selA * bfl(da.x) + selB * bfl(db.x); \
    a1 += selA * bfh(da.x) + selB * bfh(db.x); \
    a2 += selA * bfl(da.y) + selB * bfl(db.y); \
    a3 += selA * bfh(da.y) + selB * bfh(db.y); \
    a4 += selA * bfl(da.z) + selB * bfl(db.z); \
    a5 += selA * bfh(da.z) + selB * bfh(db.z); \
    a6 += selA * bfl(da.w) + selB * bfl(db.w); \
    a7 += selA * bfh(da.w) + selB * bfh(db.w); }

    int k = 0;
    for (; k + 1 < cnt; k += 2) {        // 2 cams/iter -> 4 loads in flight
      const int2 oA = offs[rec + k], oB = offs[rec + k + 1];
      const float4 wv0 = wts[rec + k], wv1 = wts[rec + k + 1];
      const uint4 dAa = *(const uint4*)(tf + (size_t)oA.x + l16);
      const uint4 dAb = *(const uint4*)(tf + (size_t)oA.y + l16);
      const uint4 dBa = *(const uint4*)(tf + (size_t)oB.x + l16);
      const uint4 dBb = *(const uint4*)(tf + (size_t)oB.y + l16);
      CAM(dAa, dAb, wv0)
      CAM(dBa, dBb, wv1)
    }
    if (k < cnt) {
      const int2 oA = offs[rec + k];
      const float4 wv0 = wts[rec + k];
      const uint4 dAa = *(const uint4*)(tf + (size_t)oA.x + l16);
      const uint4 dAb = *(const uint4*)(tf + (size_t)oA.y + l16);
      CAM(dAa, dAb, wv0)
    }
#undef CAM

    // sum the two x-halves (lane l <-> l+32)
    a0 += __shfl_xor(a0, 32); a1 += __shfl_xor(a1, 32);
    a2 += __shfl_xor(a2, 32); a3 += __shfl_xor(a3, 32);
    a4 += __shfl_xor(a4, 32); a5 += __shfl_xor(a5, 32);
    a6 += __shfl_xor(a6, 32); a7 += __shfl_xor(a7, 32);

    // lane handles channels 8*(l&31)..+7; half0 stores ch+0..3, half1 +4..7
    const int cbase = ((l & 31) << 3) + (half << 2);
    float4 vs = half ? make_float4(a4, a5, a6, a7)
                     : make_float4(a0, a1, a2, a3);
    vs.x *= inv_n; vs.y *= inv_n; vs.z *= inv_n; vs.w *= inv_n;
    *(float4*)&sm[pl][cbase] = vs;
  }
  __syncthreads();

  // write: 4 rounds; each round = 64 c-rows x 32 consecutive p (coalesced)
#pragma unroll
  for (int rd = 0; rd < 4; ++rd) {
    const int cr = rd * 64 + (tid >> 3);
    const int p4 = (tid & 7) * 4;
    const int pg = p0 + p4;
    if (pg < kP) {  // kP%4==0 -> whole float4 chunk valid
      float4 v = make_float4(sm[p4][cr], sm[p4 + 1][cr], sm[p4 + 2][cr],
                             sm[p4 + 3][cr]);
      *(float4*)(out + ((size_t)(b * kC + cr)) * kP + pg) = v;
    }
  }
}

// ---------------- Fallback (R0 kernel) if ws too small -------------------
constexpr int kCChunk = 32;
__global__ __launch_bounds__(256) void ipm_project_kernel(
    const float* __restrict__ feats, const float* __restrict__ intr,
    const float* __restrict__ c2c, float* __restrict__ out) {
  const int p = blockIdx.x * 256 + threadIdx.x;
  const int b = blockIdx.y;
  const int c0 = blockIdx.z * kCChunk;
  const bool inrange = p < kP;
  const int pi = p / kBevW;
  const int pj = p - pi * kBevW;
  const float dx = 75.2f / 188.0f;
  const float dy = 50.4f / 126.0f;
  const float xcar = 0.5f * dx + (float)pi * dx;
  const float ycar = -25.2f + 0.5f * dy + (float)pj * dy;
  int tap[kN][4];
  float tw[kN][4];
  int vmask = 0;
  const float* Kb = intr + (size_t)b * kN * 9;
  const float* Mb = c2c + (size_t)b * kN * 16;
#pragma unroll
  for (int n = 0; n < kN; ++n) {
    const float* M = Mb + n * 16;
    const float* K = Kb + n * 9;
    float Xc = M[0] * xcar + M[1] * ycar + M[3];
    float Yc = M[4] * xcar + M[5] * ycar + M[7];
    float Zc = M[8] * xcar + M[9] * ycar + M[11];
    float u = K[0] * Xc + K[1] * Yc + K[2] * Zc;
    float v = K[3] * Xc + K[4] * Yc + K[5] * Zc;
    float w = K[6] * Xc + K[7] * Yc + K[8] * Zc;
    float z = fmaxf(w, 1e-4f);
    float uf = (u / z) * 0.125f;
    float vf = (v / z) * 0.125f;
    bool valid = inrange && (Zc > 0.1f) && (uf >= 0.0f) && (uf <= 95.0f) &&
                 (vf >= 0.0f) && (vf <= 47.0f);
    if (valid) {
      float un = (uf / 95.0f) * 2.0f - 1.0f;
      float vn = (vf / 47.0f) * 2.0f - 1.0f;
      float ix = (un + 1.0f) * 0.5f * 95.0f;
      float iy = (vn + 1.0f) * 0.5f * 47.0f;
      float x0f = floorf(ix), y0f = floorf(iy);
      float wx1 = ix - x0f, wx0 = 1.0f - wx1;
      float wy1 = iy - y0f, wy0 = 1.0f - wy1;
#pragma unroll
      for (int t = 0; t < 4; ++t) {
        float xf = x0f + (float)(t & 1);
        float yf = y0f + (float)(t >> 1);
        bool inb =
            (xf >= 0.0f) && (xf <= 95.0f) && (yf >= 0.0f) && (yf <= 47.0f);
        int xi = (int)fminf(fmaxf(xf, 0.0f), 95.0f);
        int yi = (int)fminf(fmaxf(yf, 0.0f), 47.0f);
        float wgt = ((t & 1) ? wx1 : wx0) * ((t >> 1) ? wy1 : wy0);
        tap[n][t] = yi * kWf + xi;
        tw[n][t] = inb ? wgt : 0.0f;
      }
      vmask |= (1 << n);
    }
  }
  const float inv_n = 1.0f / 6.0f;
#pragma unroll 4
  for (int k = 0; k < kCChunk; ++k) {
    const int c = c0 + k;
    float acc = 0.0f;
#pragma unroll
    for (int n = 0; n < kN; ++n) {
      if (vmask & (1 << n)) {
        const float* f = feats + ((size_t)(b * kN + n) * kC + c) * kHW;
        acc += f[tap[n][0]] * tw[n][0] + f[tap[n][1]] * tw[n][1] +
               f[tap[n][2]] * tw[n][2] + f[tap[n][3]] * tw[n][3];
      }
    }
    if (inrange) out[((size_t)b * kC + c) * kP + p] = acc * inv_n;
  }
}

}  // namespace

extern "C" void kernel_launch(void* const* d_in, const int* in_sizes, int n_in,
                              void* d_out, int out_size, void* d_ws,
                              size_t ws_size, hipStream_t stream) {
  const float* feats = (const float*)d_in[0];
  const float* intr = (const float*)d_in[1];
  const float* c2c = (const float*)d_in[2];
  float* out = (float*)d_out;

  if (ws_size >= kWsNeeded && d_ws != nullptr) {
    unsigned char* wsb = (unsigned char*)d_ws;
    unsigned short* tf = (unsigned short*)wsb;
    int2* offs = (int2*)(wsb + kImgBytes);
    float4* wtsp = (float4*)(wsb + kImgBytes + kOffsBytes);
    int* cnts = (int*)(wsb + kImgBytes + kOffsBytes + kWtsBytes);

    taps_kernel<<<(kB * kP + 255) / 256, 256, 0, stream>>>(intr, c2c, offs,
                                                           wtsp, cnts);
    transpose_cvt_kernel<<<dim3(kHW / 32, kC / 64, kB * kN), 256, 0, stream>>>(
        feats, tf);
    gather_kernel<<<dim3(kNTiles, kB), 512, 0, stream>>>(
        (const unsigned char*)tf, offs, wtsp, cnts, out);
  } else {
    dim3 grid((kP + 255) / 256, kB, kC / kCChunk);
    ipm_project_kernel<<<grid, dim3(256), 0, stream>>>(feats, intr, c2c, out);
  }
}

// Round 11
// 49.201 us; speedup vs baseline: 1.9319x; 1.0778x over previous
//
#include <hip/hip_runtime.h>

namespace {

constexpr int kBevH = 188, kBevW = 126, kP = kBevH * kBevW;   // 23688
constexpr int kB = 2, kN = 6, kC = 256, kHf = 48, kWf = 96;
constexpr int kHW = kHf * kWf;                                // 4608
constexpr int kPixBytes = kC * 2;                             // 512 B bf16
constexpr int kPTile = 32;
constexpr int kNTiles = (kP + kPTile - 1) / kPTile;           // 741
constexpr size_t kImgBytes = (size_t)kB * kN * kHW * kC * 2;  // 28.3 MB bf16
constexpr size_t kWsNeeded = kImgBytes;

typedef float vfloat4 __attribute__((ext_vector_type(4)));

__device__ __forceinline__ unsigned short f2bf(float f) {     // RNE, finite
  union { float f; unsigned u; } a; a.f = f;
  unsigned r = a.u + 0x7fffu + ((a.u >> 16) & 1u);
  return (unsigned short)(r >> 16);
}
__device__ __forceinline__ float bfl(unsigned u) {
  union { unsigned u; float f; } a; a.u = u << 16; return a.f;
}
__device__ __forceinline__ float bfh(unsigned u) {
  union { unsigned u; float f; } a; a.u = u & 0xffff0000u; return a.f;
}

// ------------- K1: feats f32 [B,N,C,H,W] -> bf16 [B,N,HW,C] --------------
__global__ __launch_bounds__(256) void transpose_cvt_kernel(
    const float* __restrict__ src, unsigned short* __restrict__ dst) {
  __shared__ float tile[64][33];
  const int m = blockIdx.z;
  const int hw0 = blockIdx.x * 32;
  const int c0 = blockIdx.y * 64;
  const float* s = src + (size_t)m * kC * kHW;
  unsigned short* d = dst + (size_t)m * kHW * kC;
  const int hw = threadIdx.x & 31, cl = threadIdx.x >> 5;
#pragma unroll
  for (int k = 0; k < 8; ++k)
    tile[cl + 8 * k][hw] = s[(size_t)(c0 + cl + 8 * k) * kHW + hw0 + hw];
  __syncthreads();
  const int cp = threadIdx.x & 31, hwl = threadIdx.x >> 5;
#pragma unroll
  for (int k = 0; k < 4; ++k) {
    const int h = hwl + 8 * k;
    ushort2 uv;
    uv.x = f2bf(tile[2 * cp][h]);
    uv.y = f2bf(tile[2 * cp + 1][h]);
    *(ushort2*)(d + (size_t)(hw0 + h) * kC + c0 + 2 * cp) = uv;
  }
}

// ------------- K2: fused projection + paired-dwordx4 gather --------------
// Block = 8 waves (512 thr), 32 p, all 256 c.
// Phase 0: threads 0..191 each compute ONE (p_local, cam) record into LDS
//   (int2 pair-base offsets for y0/y1 rows + float4 half-weights); invalid
//   cams get zero records (dummy loads are L1-hot line 0, ~free).
// Main: wave w owns p = p0+4w..+3. Per (p): read 6 records via LDS
//   broadcast, issue all 12 dwordx4 loads back-to-back (deep MLP);
//   lanes<32 = x0 channels, lanes>=32 = x0+1; shfl_xor(32) sums halves.
__global__ __launch_bounds__(512) void gather_kernel(
    const unsigned char* __restrict__ tf, const float* __restrict__ intr,
    const float* __restrict__ c2c, float* __restrict__ out) {
  __shared__ float sm[kPTile][261];
  __shared__ int2 s_off[kPTile][kN];
  __shared__ float4 s_wt[kPTile][kN];

  const int b = blockIdx.y;
  // bijective XCD swizzle (m204)
  const int orig = blockIdx.x;
  constexpr int q = kNTiles / 8, r = kNTiles % 8;  // 92, 5
  const int xcd = orig & 7, idx = orig >> 3;
  const int tile = (xcd < r ? xcd * (q + 1) : r * (q + 1) + (xcd - r) * q) + idx;
  const int p0 = tile * kPTile;
  const int tid = threadIdx.x;

  // ---- phase 0: per-(p_local, cam) projection -> LDS records ----
  if (tid < kPTile * kN) {
    const int pl = tid / kN, n = tid - pl * kN;
    const int p = min(p0 + pl, kP - 1);
    const int pi = p / kBevW, pj = p - pi * kBevW;
    const float dxc = 75.2f / 188.0f, dyc = 50.4f / 126.0f;
    const float xcar = 0.5f * dxc + (float)pi * dxc;
    const float ycar = -25.2f + 0.5f * dyc + (float)pj * dyc;
    const float* M = c2c + ((size_t)b * kN + n) * 16;
    const float* K = intr + ((size_t)b * kN + n) * 9;
    float Xc = M[0] * xcar + M[1] * ycar + M[3];
    float Yc = M[4] * xcar + M[5] * ycar + M[7];
    float Zc = M[8] * xcar + M[9] * ycar + M[11];
    float u = K[0] * Xc + K[1] * Yc + K[2] * Zc;
    float v = K[3] * Xc + K[4] * Yc + K[5] * Zc;
    float w = K[6] * Xc + K[7] * Yc + K[8] * Zc;
    float z = fmaxf(w, 1e-4f);
    float uf = (u / z) * 0.125f;
    float vf = (v / z) * 0.125f;
    bool valid = (Zc > 0.1f) && (uf >= 0.0f) && (uf <= 95.0f) &&
                 (vf >= 0.0f) && (vf <= 47.0f);
    int2 ov = make_int2(0, 0);
    float4 wv = make_float4(0.f, 0.f, 0.f, 0.f);
    if (valid) {
      // reproduce reference op order (norm round-trip)
      float un = (uf / 95.0f) * 2.0f - 1.0f;
      float vn = (vf / 47.0f) * 2.0f - 1.0f;
      float ix = (un + 1.0f) * 0.5f * 95.0f;
      float iy = (vn + 1.0f) * 0.5f * 47.0f;
      float x0f = floorf(ix), y0f = floorf(iy);
      float wx1 = ix - x0f, wx0 = 1.0f - wx1;
      float wy1 = iy - y0f, wy0 = 1.0f - wy1;
      int x0i = (int)x0f;              // in [0,95]
      int y0i = (int)y0f;              // in [0,47]
      int xb = min(x0i, 94);           // pair base column
      float h0 = (x0i <= 94) ? wx0 : 0.0f;
      float h1 = (x0i <= 94) ? wx1 : wx0;
      int y1i = min(y0i + 1, 47);      // wy1==0 when clamped (iy==47.0)
      const int pix = (b * kN + n) * kHW;
      ov.x = (pix + y0i * kWf + xb) * kPixBytes;
      ov.y = (pix + y1i * kWf + xb) * kPixBytes;
      wv = make_float4(h0 * wy0, h1 * wy0, h0 * wy1, h1 * wy1);
    }
    s_off[pl][n] = ov;
    s_wt[pl][n] = wv;
  }
  __syncthreads();

  const int w = tid >> 6, l = tid & 63;
  const int half = l >> 5;
  const int l16 = l << 4;            // byte offset within the 1KB pair
  const float inv_n = 1.0f / 6.0f;

#pragma unroll
  for (int j = 0; j < 4; ++j) {
    const int pl = w * 4 + j;

    // LDS-broadcast records (uniform address per wave -> no conflicts)
    const int2 o0 = s_off[pl][0], o1 = s_off[pl][1], o2 = s_off[pl][2],
               o3 = s_off[pl][3], o4 = s_off[pl][4], o5 = s_off[pl][5];
    const float4 q0 = s_wt[pl][0], q1 = s_wt[pl][1], q2 = s_wt[pl][2],
                 q3 = s_wt[pl][3], q4 = s_wt[pl][4], q5 = s_wt[pl][5];

    // ---- issue all 12 dwordx4 loads back-to-back ----
#define LD(nm, o) \
    const uint4 nm##a = *(const uint4*)(tf + (size_t)o.x + l16); \
    const uint4 nm##b = *(const uint4*)(tf + (size_t)o.y + l16);
    LD(d0, o0) LD(d1, o1) LD(d2, o2) LD(d3, o3) LD(d4, o4) LD(d5, o5)
#undef LD

    float a0 = 0.f, a1 = 0.f, a2 = 0.f, a3 = 0.f,
          a4 = 0.f, a5 = 0.f, a6 = 0.f, a7 = 0.f;
#define CAM(da, db, wv) { \
    const float selA = half ? wv.y : wv.x; \
    const float selB = half ? wv.w : wv.z; \
    a0 += selA * bfl(da.x) + selB * bfl(db.x); \
    a1 += selA * bfh(da.x) + selB * bfh(db.x); \
    a2 += selA * bfl(da.y) + selB * bfl(db.y); \
    a3 += selA * bfh(da.y) + selB * bfh(db.y); \
    a4 += selA * bfl(da.z) + selB * bfl(db.z); \
    a5 += selA * bfh(da.z) + selB * bfh(db.z); \
    a6 += selA * bfl(da.w) + selB * bfl(db.w); \
    a7 += selA * bfh(da.w) + selB * bfh(db.w); }
    CAM(d0a, d0b, q0) CAM(d1a, d1b, q1) CAM(d2a, d2b, q2)
    CAM(d3a, d3b, q3) CAM(d4a, d4b, q4) CAM(d5a, d5b, q5)
#undef CAM

    // sum the two x-halves (lane l <-> l+32)
    a0 += __shfl_xor(a0, 32); a1 += __shfl_xor(a1, 32);
    a2 += __shfl_xor(a2, 32); a3 += __shfl_xor(a3, 32);
    a4 += __shfl_xor(a4, 32); a5 += __shfl_xor(a5, 32);
    a6 += __shfl_xor(a6, 32); a7 += __shfl_xor(a7, 32);

    // lane handles channels 8*(l&31)..+7; half0 stores ch+0..3, half1 +4..7
    const int cbase = ((l & 31) << 3) + (half << 2);
    float4 vs = half ? make_float4(a4, a5, a6, a7)
                     : make_float4(a0, a1, a2, a3);
    vs.x *= inv_n; vs.y *= inv_n; vs.z *= inv_n; vs.w *= inv_n;
    *(float4*)&sm[pl][cbase] = vs;
  }
  __syncthreads();

  // write: 4 rounds; each round = 64 c-rows x 32 consecutive p (coalesced)
#pragma unroll
  for (int rd = 0; rd < 4; ++rd) {
    const int cr = rd * 64 + (tid >> 3);
    const int p4 = (tid & 7) * 4;
    const int pg = p0 + p4;
    if (pg < kP) {  // kP%4==0 -> whole float4 chunk valid
      vfloat4 v = {sm[p4][cr], sm[p4 + 1][cr], sm[p4 + 2][cr],
                   sm[p4 + 3][cr]};
      __builtin_nontemporal_store(
          v, (vfloat4*)(out + ((size_t)(b * kC + cr)) * kP + pg));
    }
  }
}

// ---------------- Fallback (R0 kernel) if ws too small -------------------
constexpr int kCChunk = 32;
__global__ __launch_bounds__(256) void ipm_project_kernel(
    const float* __restrict__ feats, const float* __restrict__ intr,
    const float* __restrict__ c2c, float* __restrict__ out) {
  const int p = blockIdx.x * 256 + threadIdx.x;
  const int b = blockIdx.y;
  const int c0 = blockIdx.z * kCChunk;
  const bool inrange = p < kP;
  const int pi = p / kBevW;
  const int pj = p - pi * kBevW;
  const float dx = 75.2f / 188.0f;
  const float dy = 50.4f / 126.0f;
  const float xcar = 0.5f * dx + (float)pi * dx;
  const float ycar = -25.2f + 0.5f * dy + (float)pj * dy;
  int tap[kN][4];
  float tw[kN][4];
  int vmask = 0;
  const float* Kb = intr + (size_t)b * kN * 9;
  const float* Mb = c2c + (size_t)b * kN * 16;
#pragma unroll
  for (int n = 0; n < kN; ++n) {
    const float* M = Mb + n * 16;
    const float* K = Kb + n * 9;
    float Xc = M[0] * xcar + M[1] * ycar + M[3];
    float Yc = M[4] * xcar + M[5] * ycar + M[7];
    float Zc = M[8] * xcar + M[9] * ycar + M[11];
    float u = K[0] * Xc + K[1] * Yc + K[2] * Zc;
    float v = K[3] * Xc + K[4] * Yc + K[5] * Zc;
    float w = K[6] * Xc + K[7] * Yc + K[8] * Zc;
    float z = fmaxf(w, 1e-4f);
    float uf = (u / z) * 0.125f;
    float vf = (v / z) * 0.125f;
    bool valid = inrange && (Zc > 0.1f) && (uf >= 0.0f) && (uf <= 95.0f) &&
                 (vf >= 0.0f) && (vf <= 47.0f);
    if (valid) {
      float un = (uf / 95.0f) * 2.0f - 1.0f;
      float vn = (vf / 47.0f) * 2.0f - 1.0f;
      float ix = (un + 1.0f) * 0.5f * 95.0f;
      float iy = (vn + 1.0f) * 0.5f * 47.0f;
      float x0f = floorf(ix), y0f = floorf(iy);
      float wx1 = ix - x0f, wx0 = 1.0f - wx1;
      float wy1 = iy - y0f, wy0 = 1.0f - wy1;
#pragma unroll
      for (int t = 0; t < 4; ++t) {
        float xf = x0f + (float)(t & 1);
        float yf = y0f + (float)(t >> 1);
        bool inb =
            (xf >= 0.0f) && (xf <= 95.0f) && (yf >= 0.0f) && (yf <= 47.0f);
        int xi = (int)fminf(fmaxf(xf, 0.0f), 95.0f);
        int yi = (int)fminf(fmaxf(yf, 0.0f), 47.0f);
        float wgt = ((t & 1) ? wx1 : wx0) * ((t >> 1) ? wy1 : wy0);
        tap[n][t] = yi * kWf + xi;
        tw[n][t] = inb ? wgt : 0.0f;
      }
      vmask |= (1 << n);
    }
  }
  const float inv_n = 1.0f / 6.0f;
#pragma unroll 4
  for (int k = 0; k < kCChunk; ++k) {
    const int c = c0 + k;
    float acc = 0.0f;
#pragma unroll
    for (int n = 0; n < kN; ++n) {
      if (vmask & (1 << n)) {
        const float* f = feats + ((size_t)(b * kN + n) * kC + c) * kHW;
        acc += f[tap[n][0]] * tw[n][0] + f[tap[n][1]] * tw[n][1] +
               f[tap[n][2]] * tw[n][2] + f[tap[n][3]] * tw[n][3];
      }
    }
    if (inrange) out[((size_t)b * kC + c) * kP + p] = acc * inv_n;
  }
}

}  // namespace

extern "C" void kernel_launch(void* const* d_in, const int* in_sizes, int n_in,
                              void* d_out, int out_size, void* d_ws,
                              size_t ws_size, hipStream_t stream) {
  const float* feats = (const float*)d_in[0];
  const float* intr = (const float*)d_in[1];
  const float* c2c = (const float*)d_in[2];
  float* out = (float*)d_out;

  if (ws_size >= kWsNeeded && d_ws != nullptr) {
    unsigned short* tf = (unsigned short*)d_ws;
    transpose_cvt_kernel<<<dim3(kHW / 32, kC / 64, kB * kN), 256, 0, stream>>>(
        feats, tf);
    gather_kernel<<<dim3(kNTiles, kB), 512, 0, stream>>>(
        (const unsigned char*)tf, intr, c2c, out);
  } else {
    dim3 grid((kP + 255) / 256, kB, kC / kCChunk);
    ipm_project_kernel<<<grid, dim3(256), 0, stream>>>(feats, intr, c2c, out);
  }
}